// Round 9
// baseline (450.586 us; speedup 1.0000x reference)
//
#include <hip/hip_runtime.h>

#define N_IMG 128
#define BINS 128
#define HW_ELEMS (1 << 20)                 // 1024*1024 per image
#define NBLOCKS 1024                       // 4 blocks/CU x 256 CUs (co-resident)
#define CHUNK_ELEMS 4096                   // 16 KB chunk staged in LDS
#define CHUNK_V4 (CHUNK_ELEMS / 4)         // 1024 float4
#define VPT (CHUNK_V4 / 256)               // 4 float4 per thread
#define CPI 256                            // chunks per image
#define IPG (NBLOCKS / CPI)                // 4 images per group
#define NGROUPS (N_IMG / IPG)              // 32
#define NCOPY 8                            // privatized LDS hist copies (32 lanes each)
#define HPAD 132                           // 132 % 32 = 4 -> phase-shifted banks
#define NREP 8                             // global hist replicas per image
#define WSTRIDE 16                         // ull stride per image flag (128 B line)

typedef float f32x4 __attribute__((ext_vector_type(4)));

// All cross-block communication: relaxed agent-scope LOADS/STORES (concurrent,
// no coherence-point serialization) + fire-and-forget atomicAdd (no return
// wait). NO same-address RMW polls (r7 lesson), NO acquire/release fences
// (r5 lesson).
__device__ __forceinline__ void st_flag(int* p, int v) {
    __hip_atomic_store(p, v, __ATOMIC_RELAXED, __HIP_MEMORY_SCOPE_AGENT);
}
__device__ __forceinline__ int ld_flag(const int* p) {
    return __hip_atomic_load(p, __ATOMIC_RELAXED, __HIP_MEMORY_SCOPE_AGENT);
}
__device__ __forceinline__ void st_w64(unsigned long long* p, unsigned long long v) {
    __hip_atomic_store(p, v, __ATOMIC_RELAXED, __HIP_MEMORY_SCOPE_AGENT);
}
__device__ __forceinline__ unsigned long long ld_w64(const unsigned long long* p) {
    return __hip_atomic_load(p, __ATOMIC_RELAXED, __HIP_MEMORY_SCOPE_AGENT);
}

// Pipelined persistent kernel:
//   round r: hist+stage group r into stage[r&1]  |  scale group r-1 from stage[(r-1)&1]
// x crosses HBM exactly once; visibility via {stores -> syncthreads(vmcnt
// drain) -> flag store} / {load-poll -> loads}, validated in r8.
__global__ __launch_bounds__(256, 4) void fused_kernel(
    const float* __restrict__ x,
    const float* __restrict__ W1, const float* __restrict__ b1,
    const float* __restrict__ W2, const float* __restrict__ b2,
    const float* __restrict__ W3, const float* __restrict__ b3,
    const float* __restrict__ W4, const float* __restrict__ b4,
    float* __restrict__ out,
    int* __restrict__ hist2,               // [N_IMG][NREP][BINS]
    int* __restrict__ chunkdone,           // [N_IMG][CPI]
    unsigned long long* __restrict__ wflag)// [N_IMG * WSTRIDE]: bit0=ready, hi32=w bits
{
    __shared__ float stage[2][CHUNK_ELEMS];      // 32 KB
    __shared__ int   lh[NCOPY * HPAD];           // 4.2 KB
    __shared__ float h0[BINS], a1[32], a2[64], a3[BINS];
    __shared__ float wbc;

    const int t    = threadIdx.x;
    const int g    = blockIdx.x;
    const int cpy  = t >> 5;                     // 8 copies, 32 lanes each
    const int slot = g >> 8;                     // image slot 0..3 in group
    const int cin  = g & (CPI - 1);              // chunk index 0..255

    for (int r = 0; r <= NGROUPS; ++r) {
        // ---------- A: histogram + stage current group's chunk ----------
        if (r < NGROUPS) {
            const int img = r * IPG + slot;
            // issue global loads first so HBM latency hides under LDS zeroing
            const f32x4* src = (const f32x4*)(x + (size_t)img * HW_ELEMS
                                                + (size_t)cin * CHUNK_ELEMS);
            f32x4 v[VPT];
            #pragma unroll
            for (int j = 0; j < VPT; ++j) v[j] = src[j * 256 + t];

            for (int i = t; i < NCOPY * HPAD; i += 256) lh[i] = 0;
            __syncthreads();

            f32x4* stg = (f32x4*)stage[r & 1];
            #pragma unroll
            for (int j = 0; j < VPT; ++j) {
                stg[j * 256 + t] = v[j];
                #pragma unroll
                for (int k = 0; k < 4; ++k) {
                    float f = v[j][k];
                    if (f >= 0.0f && f <= 1.0f) {
                        int b = (int)(f * 128.0f);
                        b = b > 127 ? 127 : b;
                        atomicAdd(&lh[cpy * HPAD + b], 1);
                    }
                }
            }
            __syncthreads();

            if (t < BINS) {
                int s = 0;
                #pragma unroll
                for (int c = 0; c < NCOPY; ++c) s += lh[c * HPAD + t];
                // fire-and-forget device-scope add; 32 blocks per replica line
                atomicAdd(&hist2[((size_t)img * NREP + (cin & (NREP - 1))) * BINS + t], s);
            }
            __syncthreads();                 // vmcnt drain: adds complete at LLC
            if (t == 0) st_flag(&chunkdone[img * CPI + cin], 1);

            // ---------- B: rotating finisher (cin==r) runs the MLP ----------
            if (cin == r) {
                for (;;) {                   // load-poll all 256 chunk flags
                    int mine = ld_flag(&chunkdone[img * CPI + t]);
                    if (__syncthreads_and(mine)) break;
                    __builtin_amdgcn_s_sleep(2);
                }
                if (t < BINS) {
                    int s = 0;
                    #pragma unroll
                    for (int rep = 0; rep < NREP; ++rep)
                        s += ld_flag(&hist2[((size_t)img * NREP + rep) * BINS + t]);
                    h0[t] = (float)s;
                }
                __syncthreads();
                if (t < 32) {
                    float acc = b1[t];
                    #pragma unroll 8
                    for (int i = 0; i < 128; ++i) acc += h0[i] * W1[i * 32 + t];
                    a1[t] = fmaxf(acc, 0.0f);
                }
                __syncthreads();
                if (t < 64) {
                    float acc = b2[t];
                    #pragma unroll 8
                    for (int i = 0; i < 32; ++i) acc += a1[i] * W2[i * 64 + t];
                    a2[t] = fmaxf(acc, 0.0f);
                }
                __syncthreads();
                if (t < 128) {
                    float acc = b3[t];
                    #pragma unroll 8
                    for (int i = 0; i < 64; ++i) acc += a2[i] * W3[i * 128 + t];
                    a3[t] = fmaxf(acc, 0.0f);
                }
                __syncthreads();
                if (t < 64) {
                    float p = a3[t] * W4[t] + a3[t + 64] * W4[t + 64];
                    #pragma unroll
                    for (int off = 32; off > 0; off >>= 1)
                        p += __shfl_down(p, off, 64);
                    if (t == 0) {
                        float w = p + b4[0];
                        // single 64-bit store: {w bits | ready} -> no ordering barrier
                        unsigned long long fv =
                            ((unsigned long long)__float_as_uint(w) << 32) | 1ull;
                        st_w64(&wflag[(size_t)img * WSTRIDE], fv);
                    }
                }
                __syncthreads();
            }
        }

        // ---------- C: scale PREVIOUS group's chunk from LDS ----------
        if (r > 0) {
            const int img = (r - 1) * IPG + slot;
            if (t == 0) {
                unsigned long long fv;
                while (((fv = ld_w64(&wflag[(size_t)img * WSTRIDE])) & 1ull) == 0ull)
                    __builtin_amdgcn_s_sleep(2);
                wbc = __uint_as_float((unsigned)(fv >> 32));
            }
            __syncthreads();
            const float w = wbc;
            f32x4* dst = (f32x4*)(out + (size_t)img * HW_ELEMS
                                      + (size_t)cin * CHUNK_ELEMS);
            const f32x4* stg = (const f32x4*)stage[(r - 1) & 1];
            #pragma unroll
            for (int j = 0; j < VPT; ++j) {
                f32x4 vv = stg[j * 256 + t];
                vv *= w;
                __builtin_nontemporal_store(vv, &dst[j * 256 + t]);
            }
            __syncthreads();                 // wbc + stage reuse protection
        }
    }
}

extern "C" void kernel_launch(void* const* d_in, const int* in_sizes, int n_in,
                              void* d_out, int out_size, void* d_ws, size_t ws_size,
                              hipStream_t stream) {
    const float* x  = (const float*)d_in[0];
    const float* W1 = (const float*)d_in[1];
    const float* b1 = (const float*)d_in[2];
    const float* W2 = (const float*)d_in[3];
    const float* b2 = (const float*)d_in[4];
    const float* W3 = (const float*)d_in[5];
    const float* b3 = (const float*)d_in[6];
    const float* W4 = (const float*)d_in[7];
    const float* b4 = (const float*)d_in[8];
    // d_in[9] = bins (=128), hard-coded

    int* hist2     = (int*)d_ws;                                  // 512 KB
    int* chunkdone = hist2 + (size_t)N_IMG * NREP * BINS;         // 128 KB
    unsigned long long* wflag =
        (unsigned long long*)(chunkdone + (size_t)N_IMG * CPI);   // 16 KB (8B-aligned)

    // zero hist replicas + chunk flags + w flags every call
    size_t zbytes = (size_t)N_IMG * NREP * BINS * sizeof(int)
                  + (size_t)N_IMG * CPI * sizeof(int)
                  + (size_t)N_IMG * WSTRIDE * sizeof(unsigned long long);
    hipMemsetAsync(d_ws, 0, zbytes, stream);

    fused_kernel<<<NBLOCKS, 256, 0, stream>>>(x, W1, b1, W2, b2, W3, b3, W4, b4,
                                              (float*)d_out, hist2, chunkdone, wflag);
}

// Round 10
// 322.283 us; speedup vs baseline: 1.3981x; 1.3981x over previous
//
#include <hip/hip_runtime.h>

#define N_IMG 128
#define BINS 128
#define HW_ELEMS (1 << 20)                 // 1024*1024 per image
#define PARTS 8                            // blocks per image (sync domain = 8)
#define NBLOCKS (N_IMG * PARTS)            // 1024 = 4/CU x 256 CUs, co-resident
#define PART_ELEMS (HW_ELEMS / PARTS)      // 131072 elems = 512 KB per block
#define PART_V4 (PART_ELEMS / 4)           // 32768 float4
#define NCOPY 8                            // privatized LDS hist copies (32 lanes each)
#define HPAD 132                           // 132 % 32 = 4 -> phase-shifted banks
#define WSTRIDE 16                         // ull per image flag (128 B line)

typedef float f32x4 __attribute__((ext_vector_type(4)));

// Cross-block protocol (validated r8/r9): agent-scope atomic stores/loads
// (bypass non-coherent XCD L2), fire-and-forget RMW inc on a 16-writer line,
// load-only polls. No fences (r5 lesson), no contended RMW polls (r7 lesson),
// no global barriers (r9 lesson: sync domain is now 8 blocks, per image).
__device__ __forceinline__ void ag_store(int* p, int v) {
    __hip_atomic_store(p, v, __ATOMIC_RELAXED, __HIP_MEMORY_SCOPE_AGENT);
}
__device__ __forceinline__ int ag_load(const int* p) {
    return __hip_atomic_load(p, __ATOMIC_RELAXED, __HIP_MEMORY_SCOPE_AGENT);
}
__device__ __forceinline__ int rmw_inc(int* p) {
    return __hip_atomic_fetch_add(p, 1, __ATOMIC_RELAXED, __HIP_MEMORY_SCOPE_AGENT);
}
__device__ __forceinline__ void st_w64(unsigned long long* p, unsigned long long v) {
    __hip_atomic_store(p, v, __ATOMIC_RELAXED, __HIP_MEMORY_SCOPE_AGENT);
}
__device__ __forceinline__ unsigned long long ld_w64(const unsigned long long* p) {
    return __hip_atomic_load(p, __ATOMIC_RELAXED, __HIP_MEMORY_SCOPE_AGENT);
}

__global__ __launch_bounds__(256, 4) void fused_kernel(
    const float* __restrict__ x,
    const float* __restrict__ W1, const float* __restrict__ b1,
    const float* __restrict__ W2, const float* __restrict__ b2,
    const float* __restrict__ W3, const float* __restrict__ b3,
    const float* __restrict__ W4, const float* __restrict__ b4,
    float* __restrict__ out,
    int* __restrict__ parthist,            // [N_IMG][PARTS][BINS]
    int* __restrict__ done,                // [N_IMG]
    unsigned long long* __restrict__ wflag)// [N_IMG*WSTRIDE]: bit0=ready, hi32=w
{
    __shared__ int   lh[NCOPY * HPAD];     // 4.2 KB
    __shared__ float h0[BINS], a1[32], a2[64], a3[BINS];
    __shared__ int   retsh;
    __shared__ float wbc;

    const int t    = threadIdx.x;
    const int cpy  = t >> 5;               // 8 copies, 32 lanes each
    const int img  = blockIdx.x >> 3;      // PARTS = 8
    const int part = blockIdx.x & (PARTS - 1);

    for (int i = t; i < NCOPY * HPAD; i += 256) lh[i] = 0;
    __syncthreads();

    const f32x4* src = (const f32x4*)(x + (size_t)img * HW_ELEMS
                                        + (size_t)part * PART_ELEMS);

    // ---------- A: histogram my 512 KB slice ----------
    #pragma unroll 4
    for (int i = t; i < PART_V4; i += 256) {
        f32x4 v = src[i];                  // normal load: allocates in L3 for phase B
        #pragma unroll
        for (int k = 0; k < 4; ++k) {
            float f = v[k];
            if (f >= 0.0f && f <= 1.0f) {
                int b = (int)(f * 128.0f);
                b = b > 127 ? 127 : b;
                atomicAdd(&lh[cpy * HPAD + b], 1);
            }
        }
    }
    __syncthreads();

    if (t < BINS) {
        int s = 0;
        #pragma unroll
        for (int c = 0; c < NCOPY; ++c) s += lh[c * HPAD + t];
        ag_store(&parthist[((size_t)img * PARTS + part) * BINS + t], s);
    }
    __syncthreads();                       // vmcnt drain: partial stores complete
    if (t == 0) retsh = rmw_inc(&done[img]);
    __syncthreads();

    // ---------- 8th arriver runs the MLP inline (non-blocking detect) ----------
    if (retsh == PARTS - 1) {
        if (t < BINS) {
            int s = 0;
            #pragma unroll
            for (int p = 0; p < PARTS; ++p)
                s += ag_load(&parthist[((size_t)img * PARTS + p) * BINS + t]);
            h0[t] = (float)s;
        }
        __syncthreads();
        if (t < 32) {
            float acc = b1[t];
            #pragma unroll 8
            for (int i = 0; i < 128; ++i) acc += h0[i] * W1[i * 32 + t];
            a1[t] = fmaxf(acc, 0.0f);
        }
        __syncthreads();
        if (t < 64) {
            float acc = b2[t];
            #pragma unroll 8
            for (int i = 0; i < 32; ++i) acc += a1[i] * W2[i * 64 + t];
            a2[t] = fmaxf(acc, 0.0f);
        }
        __syncthreads();
        if (t < 128) {
            float acc = b3[t];
            #pragma unroll 8
            for (int i = 0; i < 64; ++i) acc += a2[i] * W3[i * 128 + t];
            a3[t] = fmaxf(acc, 0.0f);
        }
        __syncthreads();
        if (t < 64) {
            float p = a3[t] * W4[t] + a3[t + 64] * W4[t + 64];
            #pragma unroll
            for (int off = 32; off > 0; off >>= 1)
                p += __shfl_down(p, off, 64);
            if (t == 0) {
                unsigned long long fv =
                    ((unsigned long long)__float_as_uint(p + b4[0]) << 32) | 1ull;
                st_w64(&wflag[(size_t)img * WSTRIDE], fv);
            }
        }
    }

    // ---------- B: wait for MY image's w (7 siblings + ~3us MLP), rescale ----------
    if (t == 0) {
        unsigned long long fv;
        while (((fv = ld_w64(&wflag[(size_t)img * WSTRIDE])) & 1ull) == 0ull)
            __builtin_amdgcn_s_sleep(16);  // ~0.4 us granularity
        wbc = __uint_as_float((unsigned)(fv >> 32));
    }
    __syncthreads();
    const float w = wbc;

    f32x4* dst = (f32x4*)(out + (size_t)img * HW_ELEMS
                              + (size_t)part * PART_ELEMS);
    #pragma unroll 4
    for (int i = t; i < PART_V4; i += 256) {
        f32x4 v = src[i];                  // just-read -> ~50% L3 hit
        v *= w;
        __builtin_nontemporal_store(v, &dst[i]);  // no-allocate: keep x in L3
    }
}

extern "C" void kernel_launch(void* const* d_in, const int* in_sizes, int n_in,
                              void* d_out, int out_size, void* d_ws, size_t ws_size,
                              hipStream_t stream) {
    const float* x  = (const float*)d_in[0];
    const float* W1 = (const float*)d_in[1];
    const float* b1 = (const float*)d_in[2];
    const float* W2 = (const float*)d_in[3];
    const float* b2 = (const float*)d_in[4];
    const float* W3 = (const float*)d_in[5];
    const float* b3 = (const float*)d_in[6];
    const float* W4 = (const float*)d_in[7];
    const float* b4 = (const float*)d_in[8];
    // d_in[9] = bins (=128), hard-coded

    int* done = (int*)d_ws;                                   // 512 B   (zeroed)
    unsigned long long* wflag = (unsigned long long*)(done + N_IMG);  // 16 KB (zeroed)
    int* parthist = (int*)(wflag + (size_t)N_IMG * WSTRIDE);  // 512 KB (fully overwritten)

    hipMemsetAsync(d_ws, 0,
                   N_IMG * sizeof(int) + (size_t)N_IMG * WSTRIDE * sizeof(unsigned long long),
                   stream);

    fused_kernel<<<NBLOCKS, 256, 0, stream>>>(x, W1, b1, W2, b2, W3, b3, W4, b4,
                                              (float*)d_out, parthist, done, wflag);
}

// Round 12
// 310.391 us; speedup vs baseline: 1.4517x; 1.0383x over previous
//
#include <hip/hip_runtime.h>

#define N_IMG 128
#define BINS 128
#define HW_ELEMS (1 << 20)                 // 1024*1024 per image
#define PARTS 8                            // hist blocks per image
#define NBLOCKS (N_IMG * PARTS)            // 1024 = 4/CU x 256 CUs, co-resident
#define PART_ELEMS (HW_ELEMS / PARTS)      // 131072 elems = 512 KB per block
#define PART_V4 (PART_ELEMS / 4)           // 32768 float4
#define NCOPY 64                           // 4 lanes per LDS hist copy
#define HPAD 132                           // 132 % 32 = 4 -> phase-shifted banks
#define TILES_PER_IMG 32                   // 128 KB rescale tiles
#define TILE_ELEMS (HW_ELEMS / TILES_PER_IMG)  // 32768
#define TILE_V4 (TILE_ELEMS / 4)           // 8192
#define TOTAL_TILES (N_IMG * TILES_PER_IMG)    // 4096
#define NGRP 8                             // distributed pop counters
#define TPG (TOTAL_TILES / NGRP)           // 512 tiles per counter group

typedef float f32x4 __attribute__((ext_vector_type(4)));

// Validated protocol pieces: relaxed agent loads/stores (r8), fire-and-forget
// RMW on low-contention lines (r9/r10), packed 64-bit data+ready flag (r9).
// NO fences (r5), NO contended RMW polls (r7), NO global rendezvous (r10).
// r11 lesson: EVERY shared-var handoff needs read-side barrier protection on
// ALL exit paths -- the pop loop's break path raced (divergent barriers).
__device__ __forceinline__ void ag_store(int* p, int v) {
    __hip_atomic_store(p, v, __ATOMIC_RELAXED, __HIP_MEMORY_SCOPE_AGENT);
}
__device__ __forceinline__ int ag_load(const int* p) {
    return __hip_atomic_load(p, __ATOMIC_RELAXED, __HIP_MEMORY_SCOPE_AGENT);
}
__device__ __forceinline__ int rmw_inc(int* p) {
    return __hip_atomic_fetch_add(p, 1, __ATOMIC_RELAXED, __HIP_MEMORY_SCOPE_AGENT);
}
__device__ __forceinline__ void st_w64(unsigned long long* p, unsigned long long v) {
    __hip_atomic_store(p, v, __ATOMIC_RELAXED, __HIP_MEMORY_SCOPE_AGENT);
}
__device__ __forceinline__ unsigned long long ld_w64(const unsigned long long* p) {
    return __hip_atomic_load(p, __ATOMIC_RELAXED, __HIP_MEMORY_SCOPE_AGENT);
}

// ws int-offsets
#define OFF_DONE 0            // [128]
#define OFF_TAIL 128          // [1] (own 128B line)
#define OFF_CTR  160          // [8 * 32] stride-32-int lines
#define OFF_RING 416          // ring: N_IMG slots * 16 ull (128 B each)
#define RING_STRIDE 16
#define OFF_PART (416 + N_IMG * RING_STRIDE * 2)   // parthist after ring (ints)

__global__ __launch_bounds__(256, 4) void fused_kernel(
    const float* __restrict__ x,
    const float* __restrict__ W1, const float* __restrict__ b1,
    const float* __restrict__ W2, const float* __restrict__ b2,
    const float* __restrict__ W3, const float* __restrict__ b3,
    const float* __restrict__ W4, const float* __restrict__ b4,
    float* __restrict__ out, int* __restrict__ ws)
{
    __shared__ int   lh[NCOPY * HPAD];     // 33.8 KB
    __shared__ float h0[BINS], a1[32], a2[64], a3[BINS];
    __shared__ int   retsh, ksh, imgsh;
    __shared__ float wsh;

    int* done = ws + OFF_DONE;
    int* tail = ws + OFF_TAIL;
    int* ctr  = ws + OFF_CTR;
    unsigned long long* ring = (unsigned long long*)(ws + OFF_RING);
    int* parthist = ws + OFF_PART;         // [N_IMG][PARTS][BINS]

    const int t    = threadIdx.x;
    const int g    = blockIdx.x;
    const int cpy  = t >> 2;               // 64 copies, 4 lanes each
    const int img  = g >> 3;
    const int part = g & (PARTS - 1);

    // ---------------- Phase A: histogram my 512 KB slice ----------------
    for (int i = t; i < NCOPY * HPAD; i += 256) lh[i] = 0;
    __syncthreads();

    const f32x4* src = (const f32x4*)(x + (size_t)img * HW_ELEMS
                                        + (size_t)part * PART_ELEMS);
    int* myh = &lh[cpy * HPAD];
    #pragma unroll 4
    for (int i = t; i < PART_V4; i += 256) {
        f32x4 v = src[i];
        #pragma unroll
        for (int k = 0; k < 4; ++k) {
            float f = v[k];
            if (f >= 0.0f && f <= 1.0f) {
                int b = (int)(f * 128.0f);
                b = b > 127 ? 127 : b;
                atomicAdd(&myh[b], 1);
            }
        }
    }
    __syncthreads();

    if (t < BINS) {
        int s = 0;
        #pragma unroll
        for (int c = 0; c < NCOPY; ++c) s += lh[c * HPAD + t];
        ag_store(&parthist[((size_t)img * PARTS + part) * BINS + t], s);
    }
    __syncthreads();                       // vmcnt drain: partial stores complete
    if (t == 0) retsh = rmw_inc(&done[img]);
    __syncthreads();

    // ---- 8th arriver: MLP inline, append {w,img} to completion ring ----
    if (retsh == PARTS - 1) {              // retsh block-uniform, never rewritten
        if (t < BINS) {
            int s = 0;
            #pragma unroll
            for (int p = 0; p < PARTS; ++p)
                s += ag_load(&parthist[((size_t)img * PARTS + p) * BINS + t]);
            h0[t] = (float)s;
        }
        __syncthreads();
        if (t < 32) {
            float acc = b1[t];
            #pragma unroll 8
            for (int i = 0; i < 128; ++i) acc += h0[i] * W1[i * 32 + t];
            a1[t] = fmaxf(acc, 0.0f);
        }
        __syncthreads();
        if (t < 64) {
            float acc = b2[t];
            #pragma unroll 8
            for (int i = 0; i < 32; ++i) acc += a1[i] * W2[i * 64 + t];
            a2[t] = fmaxf(acc, 0.0f);
        }
        __syncthreads();
        if (t < 128) {
            float acc = b3[t];
            #pragma unroll 8
            for (int i = 0; i < 64; ++i) acc += a2[i] * W3[i * 128 + t];
            a3[t] = fmaxf(acc, 0.0f);
        }
        __syncthreads();
        if (t < 64) {
            float p = a3[t] * W4[t] + a3[t + 64] * W4[t + 64];
            #pragma unroll
            for (int off = 32; off > 0; off >>= 1)
                p += __shfl_down(p, off, 64);
            if (t == 0) {
                float w = p + b4[0];
                int pos = rmw_inc(tail);   // completion order
                unsigned long long fv =
                    ((unsigned long long)__float_as_uint(w) << 32)
                    | ((unsigned)img << 1) | 1ull;
                st_w64(&ring[(size_t)pos * RING_STRIDE], fv);
            }
        }
        __syncthreads();
    }

    // ---------------- Phase B: pop 128 KB tiles in completion order ----------------
    const int c0 = g & (NGRP - 1);
    for (int gi = 0; gi < NGRP; ++gi) {
        const int c = (c0 + gi) & (NGRP - 1);
        for (;;) {
            if (t == 0) ksh = rmw_inc(&ctr[c * 32]);   // fire-forget pop
            __syncthreads();
            const int k = ksh;
            __syncthreads();   // r11 FIX: all reads of ksh complete before t0's
                               // next write -- break path previously raced ->
                               // divergent barriers -> wrong-w tiles on replay
            if (k >= TPG) break;                       // group drained (uniform)
            const int tile = k * NGRP + c;             // stride-8: groups share ring head
            const int slot = tile >> 5;                // /TILES_PER_IMG
            const int sub  = tile & (TILES_PER_IMG - 1);

            if (t == 0) {
                unsigned long long fv;
                while (((fv = ld_w64(&ring[(size_t)slot * RING_STRIDE])) & 1ull) == 0ull)
                    __builtin_amdgcn_s_sleep(8);
                imgsh = (int)((fv >> 1) & 0x7f);
                wsh   = __uint_as_float((unsigned)(fv >> 32));
            }
            __syncthreads();
            const int   tim = imgsh;
            const float w   = wsh;

            const f32x4* s4 = (const f32x4*)(x + (size_t)tim * HW_ELEMS
                                               + (size_t)sub * TILE_ELEMS);
            f32x4* d4 = (f32x4*)(out + (size_t)tim * HW_ELEMS
                                     + (size_t)sub * TILE_ELEMS);
            #pragma unroll 8
            for (int i = t; i < TILE_V4; i += 256) {
                f32x4 v = s4[i];
                v *= w;
                __builtin_nontemporal_store(v, &d4[i]);
            }
            __syncthreads();               // imgsh/wsh reuse guard
        }
    }
}

extern "C" void kernel_launch(void* const* d_in, const int* in_sizes, int n_in,
                              void* d_out, int out_size, void* d_ws, size_t ws_size,
                              hipStream_t stream) {
    const float* x  = (const float*)d_in[0];
    const float* W1 = (const float*)d_in[1];
    const float* b1 = (const float*)d_in[2];
    const float* W2 = (const float*)d_in[3];
    const float* b2 = (const float*)d_in[4];
    const float* W3 = (const float*)d_in[5];
    const float* b3 = (const float*)d_in[6];
    const float* W4 = (const float*)d_in[7];
    const float* b4 = (const float*)d_in[8];
    // d_in[9] = bins (=128), hard-coded

    int* ws = (int*)d_ws;
    // zero done + tail + counters + ring (parthist fully overwritten each call)
    hipMemsetAsync(ws, 0, (size_t)OFF_PART * sizeof(int), stream);

    fused_kernel<<<NBLOCKS, 256, 0, stream>>>(x, W1, b1, W2, b2, W3, b3, W4, b4,
                                              (float*)d_out, ws);
}